// Round 6
// baseline (543.999 us; speedup 1.0000x reference)
//
#include <hip/hip_runtime.h>
#include <math.h>

// CapsuleLayer routing on MI355X (gfx950). fp32 in/out.
// B=64, n=2048, k=32, in_C=16, out_C=32, 3 routing iterations.
//
// Fast path: materialize priors bf16 once via MFMA (k1), layout [n][b][k][o];
// iterations 1/2 (k23) are wave-autonomous streaming passes (shfl softmax,
// no LDS/barriers). Round-6 changes: k1 8192 waves + depth-1 W/x prefetch;
// k23 8192 waves + depth-2 rotating prefetch. Round-5 counters showed both
// latency-bound (k1: 200us, VALU 6.6%, occ 28%, BW 27%).

#define BATCH 64
#define NN    2048
#define NK    32
#define NI    16
#define NO    32

#define K1_CHUNK 8            // nodes per k1 wave   -> 256 chunks
#define K23_CHUNK 16          // nodes per k23 wave  -> 128 chunks

typedef __bf16 bf16x8 __attribute__((ext_vector_type(8)));
typedef float  f32x16 __attribute__((ext_vector_type(16)));

__device__ __forceinline__ unsigned short f2bf(float f) {
    unsigned int x = __float_as_uint(f);
    unsigned int lsb = (x >> 16) & 1u;
    x += 0x7fffu + lsb;                 // RNE
    return (unsigned short)(x >> 16);
}
__device__ __forceinline__ float bflo(unsigned int u) { return __uint_as_float(u << 16); }
__device__ __forceinline__ float bfhi(unsigned int u) { return __uint_as_float(u & 0xffff0000u); }

// ---------------- fast path ----------------

// x [b][n][i] fp32 -> xT [n][b][i] bf16
__global__ __launch_bounds__(256) void xt_kernel(const float* __restrict__ xg,
                                                 unsigned short* __restrict__ xT) {
    int id = blockIdx.x * 256 + threadIdx.x;      // 524288
    int b = id >> 13;
    int rem = id & 8191;
    int n = rem >> 2;
    int i4 = rem & 3;
    float4 v = *(const float4*)(xg + ((size_t)b * NN + n) * NI + i4 * 4);
    ushort4 o;
    o.x = f2bf(v.x); o.y = f2bf(v.y); o.z = f2bf(v.z); o.w = f2bf(v.w);
    *(ushort4*)(xT + ((size_t)n * BATCH + b) * NI + i4 * 4) = o;
}

// One wave per (chunk c of 8 nodes, capsule k): 8192 waves, 1024 blocks x 8.
// A = W-frag (A[m=o][kd=i]), B = x-frag (B[kd=i][col=b]) so D[m=o][col=b]:
// col=b=lane&31, rows o=(r&3)+8*(r>>2)+4h -> ushort4 stores into
// priors[n][b][k][o]. s0 accumulated in regs (scaled 1/32 at the end).
// Depth-1 software pipeline: node j+1's W/x loads issued before node j's
// convert/MFMA/store section.
__global__ __launch_bounds__(512) void k1_kernel(
    const unsigned short* __restrict__ xT,   // bf16 [n][b][i]
    const float* __restrict__ Wg,            // fp32 [n][k][i][o]
    unsigned short* __restrict__ priors,     // bf16 [n][b][k][o]
    float* __restrict__ partial)             // fp32 [256][b][k][o]
{
    const int w    = threadIdx.x >> 6;
    const int lane = threadIdx.x & 63;
    const int task = blockIdx.x * 8 + w;     // 8192 = 256 c x 32 k
    const int k  = task & 31;
    const int c  = task >> 5;                // 0..255
    const int l5 = lane & 31;
    const int h  = lane >> 5;
    const int base = c * K1_CHUNK;

    float s0a[16], s0b[16];
#pragma unroll
    for (int r = 0; r < 16; ++r) { s0a[r] = 0.f; s0b[r] = 0.f; }

    // prefetch node base
    float wf[8];
    bf16x8 x0n, x1n;
    {
        const float* wp = Wg + ((size_t)base * NK + k) * (NI * NO) + (h * 8) * NO + l5;
#pragma unroll
        for (int j = 0; j < 8; ++j) wf[j] = wp[j * NO];
        x0n = *(const bf16x8*)(xT + (size_t)base * (BATCH * NI) + l5 * NI + h * 8);
        x1n = *(const bf16x8*)(xT + (size_t)base * (BATCH * NI) + (l5 + 32) * NI + h * 8);
    }

    for (int jj = 0; jj < K1_CHUNK; ++jj) {
        const int n = base + jj;
        float wc[8];
#pragma unroll
        for (int j = 0; j < 8; ++j) wc[j] = wf[j];
        const bf16x8 x0c = x0n, x1c = x1n;

        if (jj < K1_CHUNK - 1) {
            const int n2 = n + 1;
            const float* wp = Wg + ((size_t)n2 * NK + k) * (NI * NO) + (h * 8) * NO + l5;
#pragma unroll
            for (int j = 0; j < 8; ++j) wf[j] = wp[j * NO];
            x0n = *(const bf16x8*)(xT + (size_t)n2 * (BATCH * NI) + l5 * NI + h * 8);
            x1n = *(const bf16x8*)(xT + (size_t)n2 * (BATCH * NI) + (l5 + 32) * NI + h * 8);
        }

        union { unsigned short u[8]; bf16x8 v; } au;
#pragma unroll
        for (int j = 0; j < 8; ++j) au.u[j] = f2bf(wc[j]);

        f32x16 c0, c1;
#pragma unroll
        for (int r = 0; r < 16; ++r) { c0[r] = 0.f; c1[r] = 0.f; }
        c0 = __builtin_amdgcn_mfma_f32_32x32x16_bf16(au.v, x0c, c0, 0, 0, 0);
        c1 = __builtin_amdgcn_mfma_f32_32x32x16_bf16(au.v, x1c, c1, 0, 0, 0);

        unsigned short* p0 = priors + (((size_t)n * BATCH + l5) * NK + k) * NO;
        unsigned short* p1 = priors + (((size_t)n * BATCH + l5 + 32) * NK + k) * NO;
#pragma unroll
        for (int rg = 0; rg < 4; ++rg) {
            const int ob = 8 * rg + 4 * h;
            ushort4 s0v, s1v;
            s0v.x = f2bf(c0[4*rg+0]); s0v.y = f2bf(c0[4*rg+1]);
            s0v.z = f2bf(c0[4*rg+2]); s0v.w = f2bf(c0[4*rg+3]);
            s1v.x = f2bf(c1[4*rg+0]); s1v.y = f2bf(c1[4*rg+1]);
            s1v.z = f2bf(c1[4*rg+2]); s1v.w = f2bf(c1[4*rg+3]);
            *(ushort4*)(p0 + ob) = s0v;
            *(ushort4*)(p1 + ob) = s1v;
        }
#pragma unroll
        for (int r = 0; r < 16; ++r) { s0a[r] += c0[r]; s0b[r] += c1[r]; }
    }

    float* q0 = partial + (((size_t)c * BATCH + l5) * NK + k) * NO;
    float* q1 = partial + (((size_t)c * BATCH + l5 + 32) * NK + k) * NO;
#pragma unroll
    for (int rg = 0; rg < 4; ++rg) {
        const int ob = 8 * rg + 4 * h;
        *(float4*)(q0 + ob) = make_float4(s0a[4*rg+0] * (1.f/32.f), s0a[4*rg+1] * (1.f/32.f),
                                          s0a[4*rg+2] * (1.f/32.f), s0a[4*rg+3] * (1.f/32.f));
        *(float4*)(q1 + ob) = make_float4(s0b[4*rg+0] * (1.f/32.f), s0b[4*rg+1] * (1.f/32.f),
                                          s0b[4*rg+2] * (1.f/32.f), s0b[4*rg+3] * (1.f/32.f));
    }
}

// Iterations 1/2: one wave per (b, chunk of 16 nodes); 8192 waves.
// lane = k*2 + h(o-half). Per node: 32B/lane contiguous tile (2KB/wave),
// delta dot in regs, shfl_xor(1) pair-sum, softmax over k via shfl
// butterflies, accumulate. Depth-2 rotating prefetch.
template <int PASS>
__global__ __launch_bounds__(512) void k23_kernel(
    const unsigned short* __restrict__ priors,  // bf16 [n][b][k][o]
    const float* __restrict__ outv,             // fp32 [b][k][o]
    float* __restrict__ logits0,                // fp32 [n][b][k]
    float* __restrict__ partial)                // fp32 [128][b][k][o]
{
    const int wv   = threadIdx.x >> 6;
    const int lane = threadIdx.x & 63;
    const int task = blockIdx.x * 8 + wv;       // 8192 = 128 c x 64 b
    const int b = task & 63;
    const int c = task >> 6;                    // 0..127, 16 nodes each
    const int k = lane >> 1;
    const int h = lane & 1;

    float outr[16];
    {
        const float4* op = (const float4*)(outv + ((size_t)b * NK + k) * NO + h * 16);
#pragma unroll
        for (int q = 0; q < 4; ++q) {
            float4 v = op[q];
            outr[4*q+0] = v.x; outr[4*q+1] = v.y; outr[4*q+2] = v.z; outr[4*q+3] = v.w;
        }
    }

    float sa[16];
#pragma unroll
    for (int m = 0; m < 16; ++m) sa[m] = 0.f;

    // per-node uint4 stride: 64*32*32 ushorts / 8 = 8192
    const uint4* p = (const uint4*)(priors + ((((size_t)c * K23_CHUNK) * BATCH + b) * NK + k) * NO + h * 16);

    union Q { uint4 q[2]; unsigned u[8]; };
    Q qa, qb, qc;
    qa.q[0] = p[0];                  qa.q[1] = p[1];
    qb.q[0] = p[8192];               qb.q[1] = p[8193];

    for (int j = 0; j < K23_CHUNK; ++j) {
        const int n = c * K23_CHUNK + j;
        if (j + 2 < K23_CHUNK) {
            qc.q[0] = p[(size_t)(j + 2) * 8192];
            qc.q[1] = p[(size_t)(j + 2) * 8192 + 1];
        }
        float f[16];
#pragma unroll
        for (int m = 0; m < 8; ++m) {
            f[2*m]   = bflo(qa.u[m]);
            f[2*m+1] = bfhi(qa.u[m]);
        }
        float d = 0.f;
#pragma unroll
        for (int m = 0; m < 16; ++m) d = fmaf(f[m], outr[m], d);
        d += __shfl_xor(d, 1);

        const int li = (n * BATCH + b) * NK + k;
        float l;
        if constexpr (PASS == 1) {
            l = d;
            if (h == 0) logits0[li] = d;
        } else {
            l = logits0[li] + d;
        }
        float mx = l;
#pragma unroll
        for (int mask = 2; mask < 64; mask <<= 1)
            mx = fmaxf(mx, __shfl_xor(mx, mask));
        float e = __expf(l - mx);
        float s = e;
#pragma unroll
        for (int mask = 2; mask < 64; mask <<= 1)
            s += __shfl_xor(s, mask);
        float pr = e / s;
#pragma unroll
        for (int m = 0; m < 16; ++m) sa[m] = fmaf(pr, f[m], sa[m]);

        qa = qb; qb = qc;
    }

    float* wq = partial + (((size_t)c * BATCH + b) * NK + k) * NO + h * 16;
#pragma unroll
    for (int q = 0; q < 4; ++q)
        *(float4*)(wq + 4 * q) = make_float4(sa[4*q], sa[4*q+1], sa[4*q+2], sa[4*q+3]);
}

// Reduce partial chunks + squash. tid = b*1024 + k*32 + o.
template <int NCH>
__global__ __launch_bounds__(256) void reduce_squash_f(
    const float* __restrict__ partial,
    float* __restrict__ outf)
{
    const int tid = blockIdx.x * 256 + threadIdx.x;
    float v = 0.f;
    for (int cix = 0; cix < NCH; ++cix)
        v += partial[(size_t)cix * (BATCH * NK * NO) + tid];
    float sq = v * v;
#pragma unroll
    for (int off = 1; off < 32; off <<= 1)
        sq += __shfl_xor(sq, off);
    float coef = sq / ((1.f + sq) * sqrtf(sq));
    outf[tid] = v * coef;
}

// ---------------- legacy fallback (round-2 code, known-good 582 us) ----------------

#define LBB 32
#define LNCHUNK 8
#define LNBLK (NN / LNCHUNK)
#define LTHREADS 512
#define WK_STRIDE 516

template <int PASS>
__global__ __launch_bounds__(LTHREADS, 1) void legacy_pass(
    const float* __restrict__ xg, const float* __restrict__ Wg,
    const float* __restrict__ outv, float* __restrict__ logits,
    float* __restrict__ partial)
{
    __shared__ float w_lds[NK * WK_STRIDE];
    __shared__ float x_lds[LBB][NI + 1];
    __shared__ float delta_lds[LBB][NK + 1];
    const int t = threadIdx.x, nb = blockIdx.x, bg = blockIdx.y;
    const int b0 = bg * LBB;
    const int k = t >> 4, bq = t & 15, bl0 = bq * 2, bl1 = bq * 2 + 1;
    float acc0[NO], acc1[NO];
#pragma unroll
    for (int o = 0; o < NO; ++o) { acc0[o] = 0.f; acc1[o] = 0.f; }
    float outr0[NO], outr1[NO];
    if constexpr (PASS >= 1) {
        const float4* o0 = (const float4*)&outv[((b0 + bl0) * NK + k) * NO];
        const float4* o1 = (const float4*)&outv[((b0 + bl1) * NK + k) * NO];
#pragma unroll
        for (int q = 0; q < NO / 4; ++q) {
            float4 a = o0[q]; float4 b = o1[q];
            outr0[4*q+0]=a.x; outr0[4*q+1]=a.y; outr0[4*q+2]=a.z; outr0[4*q+3]=a.w;
            outr1[4*q+0]=b.x; outr1[4*q+1]=b.y; outr1[4*q+2]=b.z; outr1[4*q+3]=b.w;
        }
    }
    for (int j = 0; j < LNCHUNK; ++j) {
        const int n = nb * LNCHUNK + j;
        __syncthreads();
        {
            const float4* src = (const float4*)(Wg + (size_t)n * (NK * NI * NO));
#pragma unroll
            for (int r = 0; r < (NK * NI * NO / 4) / LTHREADS; ++r) {
                int idx4 = t + r * LTHREADS;
                float4 v = src[idx4];
                int e = idx4 * 4, kk = e >> 9, rem = e & 511;
                *(float4*)&w_lds[kk * WK_STRIDE + rem] = v;
            }
        }
        { int bl = t >> 4, i = t & 15;
          x_lds[bl][i] = xg[((size_t)(b0 + bl) * NN + n) * NI + i]; }
        __syncthreads();
        if constexpr (PASS == 0) {
#pragma unroll
            for (int i = 0; i < NI; ++i) {
                float xa = x_lds[bl0][i], xb = x_lds[bl1][i];
                const float* wrow = &w_lds[k * WK_STRIDE + i * NO];
#pragma unroll
                for (int o = 0; o < NO; ++o) {
                    float w = wrow[o];
                    acc0[o] = fmaf(xa, w, acc0[o]);
                    acc1[o] = fmaf(xb, w, acc1[o]);
                }
            }
        } else {
            float pr0[NO], pr1[NO];
#pragma unroll
            for (int o = 0; o < NO; ++o) { pr0[o] = 0.f; pr1[o] = 0.f; }
#pragma unroll
            for (int i = 0; i < NI; ++i) {
                float xa = x_lds[bl0][i], xb = x_lds[bl1][i];
                const float* wrow = &w_lds[k * WK_STRIDE + i * NO];
#pragma unroll
                for (int o = 0; o < NO; ++o) {
                    float w = wrow[o];
                    pr0[o] = fmaf(xa, w, pr0[o]);
                    pr1[o] = fmaf(xb, w, pr1[o]);
                }
            }
            float d0 = 0.f, d1 = 0.f;
#pragma unroll
            for (int o = 0; o < NO; ++o) {
                d0 = fmaf(pr0[o], outr0[o], d0);
                d1 = fmaf(pr1[o], outr1[o], d1);
            }
            float l0 = d0, l1 = d1;
            const size_t li0 = ((size_t)(b0 + bl0) * NN + n) * NK + k;
            const size_t li1 = ((size_t)(b0 + bl1) * NN + n) * NK + k;
            if constexpr (PASS == 2) { l0 += logits[li0]; l1 += logits[li1]; }
            else { logits[li0] = d0; logits[li1] = d1; }
            delta_lds[bl0][k] = l0; delta_lds[bl1][k] = l1;
            __syncthreads();
            float m0 = -1e30f, m1 = -1e30f;
#pragma unroll
            for (int kk = 0; kk < NK; ++kk) {
                m0 = fmaxf(m0, delta_lds[bl0][kk]);
                m1 = fmaxf(m1, delta_lds[bl1][kk]);
            }
            float s0 = 0.f, s1 = 0.f;
#pragma unroll
            for (int kk = 0; kk < NK; ++kk) {
                s0 += __expf(delta_lds[bl0][kk] - m0);
                s1 += __expf(delta_lds[bl1][kk] - m1);
            }
            float p0 = __expf(l0 - m0) / s0;
            float p1 = __expf(l1 - m1) / s1;
#pragma unroll
            for (int o = 0; o < NO; ++o) {
                acc0[o] = fmaf(p0, pr0[o], acc0[o]);
                acc1[o] = fmaf(p1, pr1[o], acc1[o]);
            }
        }
    }
    const float scale = (PASS == 0) ? (1.f / NK) : 1.f;
    float4* p0 = (float4*)&partial[(((size_t)nb * BATCH + (b0 + bl0)) * NK + k) * NO];
    float4* p1 = (float4*)&partial[(((size_t)nb * BATCH + (b0 + bl1)) * NK + k) * NO];
#pragma unroll
    for (int q = 0; q < NO / 4; ++q) {
        float4 v0, v1;
        v0.x = acc0[4*q+0]*scale; v0.y = acc0[4*q+1]*scale;
        v0.z = acc0[4*q+2]*scale; v0.w = acc0[4*q+3]*scale;
        v1.x = acc1[4*q+0]*scale; v1.y = acc1[4*q+1]*scale;
        v1.z = acc1[4*q+2]*scale; v1.w = acc1[4*q+3]*scale;
        p0[q] = v0; p1[q] = v1;
    }
}

__global__ __launch_bounds__(256) void legacy_reduce(
    const float* __restrict__ partial, float* __restrict__ outf)
{
    const int tid = blockIdx.x * 256 + threadIdx.x;
    float v = 0.f;
    for (int nb = 0; nb < LNBLK; ++nb)
        v += partial[(size_t)nb * (BATCH * NK * NO) + tid];
    float sq = v * v;
#pragma unroll
    for (int off = 1; off < 32; off <<= 1) sq += __shfl_xor(sq, off);
    float coef = sq / ((1.f + sq) * sqrtf(sq));
    outf[tid] = v * coef;
}

// ---------------- launch ----------------

extern "C" void kernel_launch(void* const* d_in, const int* in_sizes, int n_in,
                              void* d_out, int out_size, void* d_ws, size_t ws_size,
                              hipStream_t stream)
{
    const float* xg = (const float*)d_in[0];
    const float* Wg = (const float*)d_in[1];
    float* outp = (float*)d_out;
    char* ws = (char*)d_ws;

    const size_t SZ_PRIORS  = (size_t)NN * BATCH * NK * NO * 2;      // 256 MiB
    const size_t SZ_PARTIAL = (size_t)256 * BATCH * NK * NO * 4;     //  64 MiB
    const size_t SZ_LOGITS  = (size_t)NN * BATCH * NK * 4;           //  16 MiB
    const size_t SZ_XT      = (size_t)NN * BATCH * NI * 2;           //   4 MiB
    const size_t SZ_OUTV    = (size_t)BATCH * NK * NO * 4;           // 256 KiB
    const size_t NEED = SZ_PRIORS + SZ_PARTIAL + SZ_LOGITS + SZ_XT + SZ_OUTV;

    if (ws_size >= NEED) {
        unsigned short* priors = (unsigned short*)ws;
        float* partial = (float*)(ws + SZ_PRIORS);
        float* logits0 = (float*)(ws + SZ_PRIORS + SZ_PARTIAL);
        unsigned short* xT = (unsigned short*)(ws + SZ_PRIORS + SZ_PARTIAL + SZ_LOGITS);
        float* outv = (float*)(ws + SZ_PRIORS + SZ_PARTIAL + SZ_LOGITS + SZ_XT);

        xt_kernel<<<2048, 256, 0, stream>>>(xg, xT);
        k1_kernel<<<1024, 512, 0, stream>>>(xT, Wg, priors, partial);
        reduce_squash_f<256><<<256, 256, 0, stream>>>(partial, outv);
        k23_kernel<1><<<1024, 512, 0, stream>>>(priors, outv, logits0, partial);
        reduce_squash_f<128><<<256, 256, 0, stream>>>(partial, outv);
        k23_kernel<2><<<1024, 512, 0, stream>>>(priors, outv, logits0, partial);
        reduce_squash_f<128><<<256, 256, 0, stream>>>(partial, outp);
    } else {
        float* partial = (float*)ws;
        float* logits = (float*)(ws + (size_t)LNBLK * BATCH * NK * NO * 4);
        float* outv = (float*)(ws + (size_t)LNBLK * BATCH * NK * NO * 4 + (size_t)BATCH * NN * NK * 4);
        dim3 grid(LNBLK, BATCH / LBB);
        const int rblocks = BATCH * NK * NO / 256;
        legacy_pass<0><<<grid, LTHREADS, 0, stream>>>(xg, Wg, nullptr, logits, partial);
        legacy_reduce<<<rblocks, 256, 0, stream>>>(partial, outv);
        legacy_pass<1><<<grid, LTHREADS, 0, stream>>>(xg, Wg, outv, logits, partial);
        legacy_reduce<<<rblocks, 256, 0, stream>>>(partial, outv);
        legacy_pass<2><<<grid, LTHREADS, 0, stream>>>(xg, Wg, outv, logits, partial);
        legacy_reduce<<<rblocks, 256, 0, stream>>>(partial, outp);
    }
}

// Round 7
// 454.322 us; speedup vs baseline: 1.1974x; 1.1974x over previous
//
#include <hip/hip_runtime.h>
#include <math.h>

// CapsuleLayer routing on MI355X (gfx950). fp32 in/out.
// B=64, n=2048, k=32, in_C=16, out_C=32, 3 routing iterations.
//
// Fast path: materialize priors bf16 once via MFMA (k1) into [n][b][k][o];
// iterations 1/2 (k23) are wave-autonomous streaming passes (shfl softmax,
// no LDS/barriers).
// Round-7 changes:
//  * k1 reverted to round-4 MFMA orientation (A=x, B=W -> D rows=b, cols=o)
//    and stores with SCALAR ushort stores: each instruction's 64 lanes sweep
//    o -> 2 fully-written 64B lines. Round-5/6's ushort4 stores scattered
//    8B across 32 lines 2KB apart (the 226us / 6.8% VALU disease).
//  * k23: softmax max-subtraction removed (|logits| <= ~8, exp safe in fp32)
//    -> 5 fewer sequential shfl hops; node-PAIR interleaved processing with
//    depth-2-pair prefetch to hide ds-shuffle + memory latency.

#define BATCH 64
#define NN    2048
#define NK    32
#define NI    16
#define NO    32

#define K1_CHUNK 8            // nodes per k1 wave   -> 256 chunks
#define K23_CHUNK 16          // nodes per k23 wave  -> 128 chunks

typedef __bf16 bf16x8 __attribute__((ext_vector_type(8)));
typedef float  f32x16 __attribute__((ext_vector_type(16)));

__device__ __forceinline__ unsigned short f2bf(float f) {
    unsigned int x = __float_as_uint(f);
    unsigned int lsb = (x >> 16) & 1u;
    x += 0x7fffu + lsb;                 // RNE
    return (unsigned short)(x >> 16);
}
__device__ __forceinline__ float bflo(unsigned int u) { return __uint_as_float(u << 16); }
__device__ __forceinline__ float bfhi(unsigned int u) { return __uint_as_float(u & 0xffff0000u); }

// ---------------- fast path ----------------

// x [b][n][i] fp32 -> xT [n][b][i] bf16
__global__ __launch_bounds__(256) void xt_kernel(const float* __restrict__ xg,
                                                 unsigned short* __restrict__ xT) {
    int id = blockIdx.x * 256 + threadIdx.x;      // 524288
    int b = id >> 13;
    int rem = id & 8191;
    int n = rem >> 2;
    int i4 = rem & 3;
    float4 v = *(const float4*)(xg + ((size_t)b * NN + n) * NI + i4 * 4);
    ushort4 o;
    o.x = f2bf(v.x); o.y = f2bf(v.y); o.z = f2bf(v.z); o.w = f2bf(v.w);
    *(ushort4*)(xT + ((size_t)n * BATCH + b) * NI + i4 * 4) = o;
}

// One wave per (chunk c of 8 nodes, capsule k): 8192 waves, 2048 blocks x 4.
// A = x-frag (A[m=b][kd=i]), B = W-frag (B[kd=i][col=o]) => D[m=b][col=o]
// (round-4-verified orientation). Stores: scalar ushort per accumulator reg;
// lanes sweep o => 2 full 64B lines per instruction into priors[n][b][k][o].
// Depth-1 prefetch of next node's W/x.
__global__ __launch_bounds__(256) void k1_kernel(
    const unsigned short* __restrict__ xT,   // bf16 [n][b][i]
    const float* __restrict__ Wg,            // fp32 [n][k][i][o]
    unsigned short* __restrict__ priors,     // bf16 [n][b][k][o]
    float* __restrict__ partial)             // fp32 [256][b][k][o]
{
    const int w    = threadIdx.x >> 6;       // 0..3
    const int lane = threadIdx.x & 63;
    const int task = blockIdx.x * 4 + w;     // 8192 = 256 c x 32 k
    const int k  = task & 31;
    const int c  = task >> 5;                // 0..255
    const int l5 = lane & 31;                // o (B col); also x-row select
    const int h  = lane >> 5;
    const int base = c * K1_CHUNK;

    float s0a[16], s0b[16];
#pragma unroll
    for (int r = 0; r < 16; ++r) { s0a[r] = 0.f; s0b[r] = 0.f; }

    // prefetch node `base`
    float wf[8];
    bf16x8 x0n, x1n;
    {
        const float* wp = Wg + ((size_t)base * NK + k) * (NI * NO) + (h * 8) * NO + l5;
#pragma unroll
        for (int j = 0; j < 8; ++j) wf[j] = wp[j * NO];
        x0n = *(const bf16x8*)(xT + (size_t)base * (BATCH * NI) + l5 * NI + h * 8);
        x1n = *(const bf16x8*)(xT + (size_t)base * (BATCH * NI) + (l5 + 32) * NI + h * 8);
    }

    for (int jj = 0; jj < K1_CHUNK; ++jj) {
        const int n = base + jj;
        float wc[8];
#pragma unroll
        for (int j = 0; j < 8; ++j) wc[j] = wf[j];
        const bf16x8 x0c = x0n, x1c = x1n;

        if (jj < K1_CHUNK - 1) {
            const int n2 = n + 1;
            const float* wp = Wg + ((size_t)n2 * NK + k) * (NI * NO) + (h * 8) * NO + l5;
#pragma unroll
            for (int j = 0; j < 8; ++j) wf[j] = wp[j * NO];
            x0n = *(const bf16x8*)(xT + (size_t)n2 * (BATCH * NI) + l5 * NI + h * 8);
            x1n = *(const bf16x8*)(xT + (size_t)n2 * (BATCH * NI) + (l5 + 32) * NI + h * 8);
        }

        union { unsigned short u[8]; bf16x8 v; } bu;
#pragma unroll
        for (int j = 0; j < 8; ++j) bu.u[j] = f2bf(wc[j]);

        f32x16 c0, c1;
#pragma unroll
        for (int r = 0; r < 16; ++r) { c0[r] = 0.f; c1[r] = 0.f; }
        // A=x rows b (c0: b=0..31, c1: b=32..63), B=W cols o
        c0 = __builtin_amdgcn_mfma_f32_32x32x16_bf16(x0c, bu.v, c0, 0, 0, 0);
        c1 = __builtin_amdgcn_mfma_f32_32x32x16_bf16(x1c, bu.v, c1, 0, 0, 0);

        // priors index: n*65536 + b*1024 + k*32 + o
        unsigned short* pp = priors + (size_t)n * (BATCH * NK * NO) + k * NO + l5;
#pragma unroll
        for (int r = 0; r < 16; ++r) {
            const int b = (r & 3) + 8 * (r >> 2) + 4 * h;   // D row (m74/m101)
            pp[(size_t)b * (NK * NO)] = f2bf(c0[r]);
            pp[(size_t)(b + 32) * (NK * NO)] = f2bf(c1[r]);
            s0a[r] += c0[r];
            s0b[r] += c1[r];
        }
    }

    float* q = partial + (size_t)c * (BATCH * NK * NO) + k * NO + l5;
#pragma unroll
    for (int r = 0; r < 16; ++r) {
        const int b = (r & 3) + 8 * (r >> 2) + 4 * h;
        q[(size_t)b * (NK * NO)] = s0a[r] * (1.f / 32.f);
        q[(size_t)(b + 32) * (NK * NO)] = s0b[r] * (1.f / 32.f);
    }
}

// Iterations 1/2: one wave per (b, chunk of 16 nodes); 8192 waves.
// lane = k*2 + h(o-half). Per node: 32B/lane contiguous (2KB/wave).
// Softmax WITHOUT max-subtraction (|logits| <= ~8): exp -> 5-hop shfl sum.
// Node pairs processed interleaved; prefetch 2 pairs (4 nodes) ahead.
template <int PASS>
__global__ __launch_bounds__(256) void k23_kernel(
    const unsigned short* __restrict__ priors,  // bf16 [n][b][k][o]
    const float* __restrict__ outv,             // fp32 [b][k][o]
    float* __restrict__ logits0,                // fp32 [n][b][k]
    float* __restrict__ partial)                // fp32 [128][b][k][o]
{
    const int wv   = threadIdx.x >> 6;
    const int lane = threadIdx.x & 63;
    const int task = blockIdx.x * 4 + wv;       // 8192 = 128 c x 64 b
    const int b = task & 63;
    const int c = task >> 6;                    // 0..127, 16 nodes each
    const int k = lane >> 1;
    const int h = lane & 1;

    float outr[16];
    {
        const float4* op = (const float4*)(outv + ((size_t)b * NK + k) * NO + h * 16);
#pragma unroll
        for (int q = 0; q < 4; ++q) {
            float4 v = op[q];
            outr[4*q+0] = v.x; outr[4*q+1] = v.y; outr[4*q+2] = v.z; outr[4*q+3] = v.w;
        }
    }

    float sa[16];
#pragma unroll
    for (int m = 0; m < 16; ++m) sa[m] = 0.f;

    // node stride in uint4: 64*32*32 ushorts / 8 = 8192
    const uint4* p = (const uint4*)(priors +
        (((size_t)(c * K23_CHUNK) * BATCH + b) * NK + k) * NO + h * 16);
    float* lg = logits0 + ((size_t)(c * K23_CHUNK) * BATCH + b) * NK + k;  // node stride 2048 floats

    union Q { uint4 q[2]; unsigned u[8]; };
    Q a0, a1, n0, n1;
    float la0 = 0.f, la1 = 0.f, ln0 = 0.f, ln1 = 0.f;
    a0.q[0] = p[0];          a0.q[1] = p[1];
    a1.q[0] = p[8192];       a1.q[1] = p[8193];
    n0.q[0] = p[2 * 8192];   n0.q[1] = p[2 * 8192 + 1];
    n1.q[0] = p[3 * 8192];   n1.q[1] = p[3 * 8192 + 1];
    if constexpr (PASS == 2) {
        la0 = lg[0];        la1 = lg[2048];
        ln0 = lg[2 * 2048]; ln1 = lg[3 * 2048];
    }

    for (int jp = 0; jp < K23_CHUNK / 2; ++jp) {
        Q w0 = a0, w1 = a1;
        a0 = n0; a1 = n1;
        float g0 = la0, g1 = la1;
        la0 = ln0; la1 = ln1;
        if (jp < K23_CHUNK / 2 - 2) {
            const size_t n4 = (size_t)(2 * jp + 4), n5 = (size_t)(2 * jp + 5);
            n0.q[0] = p[n4 * 8192]; n0.q[1] = p[n4 * 8192 + 1];
            n1.q[0] = p[n5 * 8192]; n1.q[1] = p[n5 * 8192 + 1];
            if constexpr (PASS == 2) { ln0 = lg[n4 * 2048]; ln1 = lg[n5 * 2048]; }
        }

        float f0[16], f1[16];
#pragma unroll
        for (int m = 0; m < 8; ++m) {
            f0[2*m]   = bflo(w0.u[m]);
            f0[2*m+1] = bfhi(w0.u[m]);
            f1[2*m]   = bflo(w1.u[m]);
            f1[2*m+1] = bfhi(w1.u[m]);
        }
        float d0 = 0.f, d1 = 0.f;
#pragma unroll
        for (int m = 0; m < 16; ++m) {
            d0 = fmaf(f0[m], outr[m], d0);
            d1 = fmaf(f1[m], outr[m], d1);
        }
        d0 += __shfl_xor(d0, 1);
        d1 += __shfl_xor(d1, 1);

        float l0, l1;
        if constexpr (PASS == 1) {
            l0 = d0; l1 = d1;
            if (h == 0) {
                lg[(size_t)(2 * jp) * 2048] = d0;      // 32 lanes -> 128B contiguous
                lg[(size_t)(2 * jp + 1) * 2048] = d1;
            }
        } else {
            l0 = g0 + d0;
            l1 = g1 + d1;
        }
        // softmax over k, no max-subtraction (|l| <= ~8, fp32-safe)
        float e0 = __expf(l0), e1 = __expf(l1);
        float s0 = e0, s1 = e1;
#pragma unroll
        for (int mask = 2; mask < 64; mask <<= 1) {
            s0 += __shfl_xor(s0, mask);
            s1 += __shfl_xor(s1, mask);
        }
        float p0 = e0 / s0;
        float p1 = e1 / s1;
#pragma unroll
        for (int m = 0; m < 16; ++m) {
            sa[m] = fmaf(p0, f0[m], sa[m]);
            sa[m] = fmaf(p1, f1[m], sa[m]);
        }
    }

    float* wq = partial + (((size_t)c * BATCH + b) * NK + k) * NO + h * 16;
#pragma unroll
    for (int q = 0; q < 4; ++q)
        *(float4*)(wq + 4 * q) = make_float4(sa[4*q], sa[4*q+1], sa[4*q+2], sa[4*q+3]);
}

// Reduce partial chunks + squash. tid = b*1024 + k*32 + o.
template <int NCH>
__global__ __launch_bounds__(256) void reduce_squash_f(
    const float* __restrict__ partial,
    float* __restrict__ outf)
{
    const int tid = blockIdx.x * 256 + threadIdx.x;
    float v = 0.f;
    for (int cix = 0; cix < NCH; ++cix)
        v += partial[(size_t)cix * (BATCH * NK * NO) + tid];
    float sq = v * v;
#pragma unroll
    for (int off = 1; off < 32; off <<= 1)
        sq += __shfl_xor(sq, off);
    float coef = sq / ((1.f + sq) * sqrtf(sq));
    outf[tid] = v * coef;
}

// ---------------- legacy fallback (round-2 code, known-good 582 us) ----------------

#define LBB 32
#define LNCHUNK 8
#define LNBLK (NN / LNCHUNK)
#define LTHREADS 512
#define WK_STRIDE 516

template <int PASS>
__global__ __launch_bounds__(LTHREADS, 1) void legacy_pass(
    const float* __restrict__ xg, const float* __restrict__ Wg,
    const float* __restrict__ outv, float* __restrict__ logits,
    float* __restrict__ partial)
{
    __shared__ float w_lds[NK * WK_STRIDE];
    __shared__ float x_lds[LBB][NI + 1];
    __shared__ float delta_lds[LBB][NK + 1];
    const int t = threadIdx.x, nb = blockIdx.x, bg = blockIdx.y;
    const int b0 = bg * LBB;
    const int k = t >> 4, bq = t & 15, bl0 = bq * 2, bl1 = bq * 2 + 1;
    float acc0[NO], acc1[NO];
#pragma unroll
    for (int o = 0; o < NO; ++o) { acc0[o] = 0.f; acc1[o] = 0.f; }
    float outr0[NO], outr1[NO];
    if constexpr (PASS >= 1) {
        const float4* o0 = (const float4*)&outv[((b0 + bl0) * NK + k) * NO];
        const float4* o1 = (const float4*)&outv[((b0 + bl1) * NK + k) * NO];
#pragma unroll
        for (int q = 0; q < NO / 4; ++q) {
            float4 a = o0[q]; float4 b = o1[q];
            outr0[4*q+0]=a.x; outr0[4*q+1]=a.y; outr0[4*q+2]=a.z; outr0[4*q+3]=a.w;
            outr1[4*q+0]=b.x; outr1[4*q+1]=b.y; outr1[4*q+2]=b.z; outr1[4*q+3]=b.w;
        }
    }
    for (int j = 0; j < LNCHUNK; ++j) {
        const int n = nb * LNCHUNK + j;
        __syncthreads();
        {
            const float4* src = (const float4*)(Wg + (size_t)n * (NK * NI * NO));
#pragma unroll
            for (int r = 0; r < (NK * NI * NO / 4) / LTHREADS; ++r) {
                int idx4 = t + r * LTHREADS;
                float4 v = src[idx4];
                int e = idx4 * 4, kk = e >> 9, rem = e & 511;
                *(float4*)&w_lds[kk * WK_STRIDE + rem] = v;
            }
        }
        { int bl = t >> 4, i = t & 15;
          x_lds[bl][i] = xg[((size_t)(b0 + bl) * NN + n) * NI + i]; }
        __syncthreads();
        if constexpr (PASS == 0) {
#pragma unroll
            for (int i = 0; i < NI; ++i) {
                float xa = x_lds[bl0][i], xb = x_lds[bl1][i];
                const float* wrow = &w_lds[k * WK_STRIDE + i * NO];
#pragma unroll
                for (int o = 0; o < NO; ++o) {
                    float w = wrow[o];
                    acc0[o] = fmaf(xa, w, acc0[o]);
                    acc1[o] = fmaf(xb, w, acc1[o]);
                }
            }
        } else {
            float pr0[NO], pr1[NO];
#pragma unroll
            for (int o = 0; o < NO; ++o) { pr0[o] = 0.f; pr1[o] = 0.f; }
#pragma unroll
            for (int i = 0; i < NI; ++i) {
                float xa = x_lds[bl0][i], xb = x_lds[bl1][i];
                const float* wrow = &w_lds[k * WK_STRIDE + i * NO];
#pragma unroll
                for (int o = 0; o < NO; ++o) {
                    float w = wrow[o];
                    pr0[o] = fmaf(xa, w, pr0[o]);
                    pr1[o] = fmaf(xb, w, pr1[o]);
                }
            }
            float d0 = 0.f, d1 = 0.f;
#pragma unroll
            for (int o = 0; o < NO; ++o) {
                d0 = fmaf(pr0[o], outr0[o], d0);
                d1 = fmaf(pr1[o], outr1[o], d1);
            }
            float l0 = d0, l1 = d1;
            const size_t li0 = ((size_t)(b0 + bl0) * NN + n) * NK + k;
            const size_t li1 = ((size_t)(b0 + bl1) * NN + n) * NK + k;
            if constexpr (PASS == 2) { l0 += logits[li0]; l1 += logits[li1]; }
            else { logits[li0] = d0; logits[li1] = d1; }
            delta_lds[bl0][k] = l0; delta_lds[bl1][k] = l1;
            __syncthreads();
            float m0 = -1e30f, m1 = -1e30f;
#pragma unroll
            for (int kk = 0; kk < NK; ++kk) {
                m0 = fmaxf(m0, delta_lds[bl0][kk]);
                m1 = fmaxf(m1, delta_lds[bl1][kk]);
            }
            float s0 = 0.f, s1 = 0.f;
#pragma unroll
            for (int kk = 0; kk < NK; ++kk) {
                s0 += __expf(delta_lds[bl0][kk] - m0);
                s1 += __expf(delta_lds[bl1][kk] - m1);
            }
            float p0 = __expf(l0 - m0) / s0;
            float p1 = __expf(l1 - m1) / s1;
#pragma unroll
            for (int o = 0; o < NO; ++o) {
                acc0[o] = fmaf(p0, pr0[o], acc0[o]);
                acc1[o] = fmaf(p1, pr1[o], acc1[o]);
            }
        }
    }
    const float scale = (PASS == 0) ? (1.f / NK) : 1.f;
    float4* p0 = (float4*)&partial[(((size_t)nb * BATCH + (b0 + bl0)) * NK + k) * NO];
    float4* p1 = (float4*)&partial[(((size_t)nb * BATCH + (b0 + bl1)) * NK + k) * NO];
#pragma unroll
    for (int q = 0; q < NO / 4; ++q) {
        float4 v0, v1;
        v0.x = acc0[4*q+0]*scale; v0.y = acc0[4*q+1]*scale;
        v0.z = acc0[4*q+2]*scale; v0.w = acc0[4*q+3]*scale;
        v1.x = acc1[4*q+0]*scale; v1.y = acc1[4*q+1]*scale;
        v1.z = acc1[4*q+2]*scale; v1.w = acc1[4*q+3]*scale;
        p0[q] = v0; p1[q] = v1;
    }
}

__global__ __launch_bounds__(256) void legacy_reduce(
    const float* __restrict__ partial, float* __restrict__ outf)
{
    const int tid = blockIdx.x * 256 + threadIdx.x;
    float v = 0.f;
    for (int nb = 0; nb < LNBLK; ++nb)
        v += partial[(size_t)nb * (BATCH * NK * NO) + tid];
    float sq = v * v;
#pragma unroll
    for (int off = 1; off < 32; off <<= 1) sq += __shfl_xor(sq, off);
    float coef = sq / ((1.f + sq) * sqrtf(sq));
    outf[tid] = v * coef;
}

// ---------------- launch ----------------

extern "C" void kernel_launch(void* const* d_in, const int* in_sizes, int n_in,
                              void* d_out, int out_size, void* d_ws, size_t ws_size,
                              hipStream_t stream)
{
    const float* xg = (const float*)d_in[0];
    const float* Wg = (const float*)d_in[1];
    float* outp = (float*)d_out;
    char* ws = (char*)d_ws;

    const size_t SZ_PRIORS  = (size_t)NN * BATCH * NK * NO * 2;      // 256 MiB
    const size_t SZ_PARTIAL = (size_t)256 * BATCH * NK * NO * 4;     //  64 MiB
    const size_t SZ_LOGITS  = (size_t)NN * BATCH * NK * 4;           //  16 MiB
    const size_t SZ_XT      = (size_t)NN * BATCH * NI * 2;           //   4 MiB
    const size_t SZ_OUTV    = (size_t)BATCH * NK * NO * 4;           // 256 KiB
    const size_t NEED = SZ_PRIORS + SZ_PARTIAL + SZ_LOGITS + SZ_XT + SZ_OUTV;

    if (ws_size >= NEED) {
        unsigned short* priors = (unsigned short*)ws;
        float* partial = (float*)(ws + SZ_PRIORS);
        float* logits0 = (float*)(ws + SZ_PRIORS + SZ_PARTIAL);
        unsigned short* xT = (unsigned short*)(ws + SZ_PRIORS + SZ_PARTIAL + SZ_LOGITS);
        float* outv = (float*)(ws + SZ_PRIORS + SZ_PARTIAL + SZ_LOGITS + SZ_XT);

        xt_kernel<<<2048, 256, 0, stream>>>(xg, xT);
        k1_kernel<<<2048, 256, 0, stream>>>(xT, Wg, priors, partial);
        reduce_squash_f<256><<<256, 256, 0, stream>>>(partial, outv);
        k23_kernel<1><<<2048, 256, 0, stream>>>(priors, outv, logits0, partial);
        reduce_squash_f<128><<<256, 256, 0, stream>>>(partial, outv);
        k23_kernel<2><<<2048, 256, 0, stream>>>(priors, outv, logits0, partial);
        reduce_squash_f<128><<<256, 256, 0, stream>>>(partial, outp);
    } else {
        float* partial = (float*)ws;
        float* logits = (float*)(ws + (size_t)LNBLK * BATCH * NK * NO * 4);
        float* outv = (float*)(ws + (size_t)LNBLK * BATCH * NK * NO * 4 + (size_t)BATCH * NN * NK * 4);
        dim3 grid(LNBLK, BATCH / LBB);
        const int rblocks = BATCH * NK * NO / 256;
        legacy_pass<0><<<grid, LTHREADS, 0, stream>>>(xg, Wg, nullptr, logits, partial);
        legacy_reduce<<<rblocks, 256, 0, stream>>>(partial, outv);
        legacy_pass<1><<<grid, LTHREADS, 0, stream>>>(xg, Wg, outv, logits, partial);
        legacy_reduce<<<rblocks, 256, 0, stream>>>(partial, outv);
        legacy_pass<2><<<grid, LTHREADS, 0, stream>>>(xg, Wg, outv, logits, partial);
        legacy_reduce<<<rblocks, 256, 0, stream>>>(partial, outp);
    }
}